// Round 16
// baseline (613.469 us; speedup 1.0000x reference)
//
#include <hip/hip_runtime.h>
#include <math.h>
#include <float.h>
#include <type_traits>

typedef _Float16 f16x8 __attribute__((ext_vector_type(8)));
typedef _Float16 f16x2 __attribute__((ext_vector_type(2)));
typedef _Float16 f16x4 __attribute__((ext_vector_type(4)));
typedef __fp16   h16x2 __attribute__((ext_vector_type(2)));   // cvt_pkrtz return type
typedef float    f32x4 __attribute__((ext_vector_type(4)));

#define N_BATCH 256

// Tap->slot table (r14-verified conflict-engineered permutation; wid-invariant
// bank windows). Slots j0,j1 / j2,j3 = phases of pair-reads RP1/RP2 (delta 128
// dwords = ci -> ci+1 at 4-row slices); j4..j7 = singles. t = 9*ci+3*kh+kw;
// negative = pad (bank class -t, A weight 0); -1 = pure zero slot.
#define TAP_TABLE                                            \
    { { 0,  9,  2, 11, 18, 20, 22,  4},   /* g0 */           \
      { 6, 15,  8, 17, 24, 26,-25, 13},   /* g1 */           \
      { 1, 10,  3, 12, 19, 21, 23,  5},   /* g2 */           \
      { 7, 16,-24, -1, 25,-24,-26, 14} }  /* g3 */

static __device__ __forceinline__ f32x4 MM(f16x8 a, f16x8 b, f32x4 c) {
    return __builtin_amdgcn_mfma_f32_16x16x32_f16(a, b, c, 0, 0, 0);
}
static __device__ __forceinline__ f16x2 pkrtz(float a, float b) {
    h16x2 r = __builtin_amdgcn_cvt_pkrtz(a, b);
    return __builtin_bit_cast(f16x2, r);
}

// A-fragments (fp16 RTN): set f = kd*2 + cht (6 sets); dword i = f*256 + lane*4 + r.
// Lane l holds A[ch = cht*16 + (l&15)][slot (g=l>>4, j=2r+half)] = weight of tap
// TAP[g][j] (0 for pads). Must match the kernel's B-side gather.
__global__ void prep_weights(const float* __restrict__ w, unsigned* __restrict__ ws) {
    static constexpr int TAP[4][8] = TAP_TABLE;
    int i = blockIdx.x * 256 + threadIdx.x;          // 1536 dwords
    if (i >= 1536) return;
    int f = i >> 8, rem = i & 255;
    int lane = rem >> 2, r = rem & 3;
    int kd = f >> 1, cht = f & 1;
    int g = lane >> 4, chl = lane & 15;
    int ch = cht * 16 + chl;
    unsigned outv = 0;
    for (int half = 0; half < 2; ++half) {
        int t = TAP[g][2 * r + half];
        unsigned short bits = 0;                     // exact zero for pad slots
        if (ch < 24 && t >= 0) {
            int ci = t / 9, rr = t % 9, kh = rr / 3, kw = rr % 3;
            union { _Float16 h; unsigned short u; } cv;
            cv.h = (_Float16)w[(((ch * 3 + ci) * 3 + kd) * 3 + kh) * 3 + kw];
            bits = cv.u;
        }
        outv |= (unsigned)bits << (16 * half);
    }
    ws[i] = outv;
}

__global__ __launch_bounds__(128, 6) void conv_mfma(
    const float* __restrict__ x, const char* __restrict__ wsp,
    const float* __restrict__ bias, float* __restrict__ out)
{
    static constexpr int TAP[4][8] = TAP_TABLE;
    // 5-slot ring of SHARED slices: [slot][ci 0..2][row 0..3][col 0..31], row-rotated
    __shared__ __align__(16) float xs[5 * 384];      // 7680 B

    const int tid  = threadIdx.x;                    // 0..127, 2 waves
    const int lane = tid & 63;
    const int wid  = tid >> 6;                       // 0..1
    const int g = lane >> 4, m = lane & 15;
    // XCD-bijective swizzle (3840 % 8 == 0): XCD k owns n in [32k, 32k+32)
    const int lb = (blockIdx.x & 7) * 480 + (blockIdx.x >> 3);
    const int n  = lb / 15;
    const int h0 = (lb - n * 15) * 2;                // h-tile base: 0,2,...,28
    const int h  = h0 + wid;                         // 0..29, always valid

    // ---- staging: wave0 -> ci0,ci1 (64 lanes); wave1 -> ci2 (lanes<32).
    // Rows h0..h0+3 <= 31 always. Pre-rotated source cols (rot = 8*(row&3)).
    const int ciS  = (wid == 0) ? (lane >> 5) : 2;
    const int rS   = (lane >> 3) & 3;                // slot row 0..3
    const int c4S  = (lane & 7) * 4;
    const int colS = (c4S - 8 * rS) & 31;            // 4-blocks never wrap
    const bool sAct = (wid == 0) || (lane < 32);
    const char* gsb = (const char*)(x + ((size_t)(n * 3 + ciS) * 32768
                                          + (size_t)(h0 + rS) * 32 + colS));

    auto stageTo = [&](int slotFl, int s) {          // one DMA instr per wave
        if (sAct)
            __builtin_amdgcn_global_load_lds(
                (const __attribute__((address_space(1))) unsigned*)(gsb + (size_t)s * 4096),
                (__attribute__((address_space(3))) unsigned*)(xs + slotFl + wid * 256),
                16, 0, 0);
    };

    // ---- gather addresses: byte offset within a slot for tap t (wt variant)
    auto mkidx = [&](int t, int wt) -> unsigned {
        if (t >= 0) {
            int ci = t / 9, rr = t % 9, kh = rr / 3, kw = rr % 3;
            int row = wid + kh;                      // 0..3
            int col = (m + wt * 14 + kw + 8 * (row & 3)) & 31;
            return (unsigned)((ci * 128 + row * 32 + col) * 4);
        } else {                                     // pad: engineered bank class
            int V = -t;                              // 24..26
            int col = (m + wt * 14 + V + 8 * (wid & 3)) & 31;
            return (unsigned)((wid * 32 + col) * 4); // row<=1 of ci0: staged, finite
        }
    };
    unsigned bp[2][2], apoS[2][4];
#pragma unroll
    for (int wt = 0; wt < 2; ++wt) {
        bp[wt][0] = mkidx(TAP[g][0], wt);            // RP1 base (phase1 = +128 dwords)
        bp[wt][1] = mkidx(TAP[g][2], wt);            // RP2 base
#pragma unroll
        for (int j = 0; j < 4; ++j) apoS[wt][j] = mkidx(TAP[g][4 + j], wt);
    }

    // ---- preload 6 A-fragments (loop-invariant, 24 VGPRs)
    const char* wl = wsp + (size_t)lane * 16;
    f16x8 aH[3][2];
#pragma unroll
    for (int kd = 0; kd < 3; ++kd)
#pragma unroll
        for (int cht = 0; cht < 2; ++cht)
            aH[kd][cht] = *(const f16x8*)(wl + (size_t)(kd * 2 + cht) * 1024);

    f32x4 acc[3][2][2];                              // [depth%3][cht][wt]; fresh at kd=0
    f32x4 mn[2][2];
#pragma unroll
    for (int b = 0; b < 2; ++b)
#pragma unroll
        for (int c = 0; c < 2; ++c) mn[b][c] = (f32x4){FLT_MAX, FLT_MAX, FLT_MAX, FLT_MAX};
    const f32x4 ZR = (f32x4){0.f, 0.f, 0.f, 0.f};

    stageTo(0, 0); stageTo(384, 1); stageTo(768, 2); stageTo(1152, 3);  // 3-deep prologue

    const char* xb = (const char*)xs;

    auto step = [&](auto sc) {
        constexpr int  S    = decltype(sc)::value;
        constexpr int  SLOT = (S % 5) * 1536;        // byte offset of slice S
        constexpr int  SM   = S % 3;
        constexpr bool K0 = (S <= 29), K1 = (S >= 1 && S <= 30), K2 = (S >= 2);

        // drain own DMA for slice S; keep 3 youngest prefetches in flight
        if constexpr (S <= 28)      asm volatile("s_waitcnt vmcnt(3)\ns_barrier" ::: "memory");
        else if constexpr (S == 29) asm volatile("s_waitcnt vmcnt(2)\ns_barrier" ::: "memory");
        else if constexpr (S == 30) asm volatile("s_waitcnt vmcnt(1)\ns_barrier" ::: "memory");
        else                        asm volatile("s_waitcnt vmcnt(0)\ns_barrier" ::: "memory");
        if constexpr (S + 4 <= 31) stageTo(((S + 4) % 5) * 384, S + 4);  // retired slot
        __builtin_amdgcn_sched_barrier(0);

        {
#pragma unroll
            for (int wt = 0; wt < 2; ++wt) {
                float xv[8];
                // pair reads: ds_read2_b32 offset0:0 offset1:128 (delta ci->ci+1)
                const float* q0 = (const float*)(xb + SLOT + bp[wt][0]);
                xv[0] = q0[0]; xv[1] = q0[128];
                const float* q1 = (const float*)(xb + SLOT + bp[wt][1]);
                xv[2] = q1[0]; xv[3] = q1[128];
#pragma unroll
                for (int j = 0; j < 4; ++j)          // singles (imm-offset b32)
                    xv[4 + j] = *(const float*)(xb + SLOT + apoS[wt][j]);
                f16x2 p0 = pkrtz(xv[0], xv[1]);
                f16x2 p1 = pkrtz(xv[2], xv[3]);
                f16x2 p2 = pkrtz(xv[4], xv[5]);
                f16x2 p3 = pkrtz(xv[6], xv[7]);
                f16x4 lo = __builtin_shufflevector(p0, p1, 0, 1, 2, 3);
                f16x4 hi = __builtin_shufflevector(p2, p3, 0, 1, 2, 3);
                f16x8 bf = __builtin_shufflevector(lo, hi, 0, 1, 2, 3, 4, 5, 6, 7);
                if constexpr (K0) {                  // fresh depth S from zero C
                    acc[SM][0][wt] = MM(aH[0][0], bf, ZR);
                    acc[SM][1][wt] = MM(aH[0][1], bf, ZR);
                }
                if constexpr (K1) {
                    constexpr int S1 = (SM + 2) % 3;
                    acc[S1][0][wt] = MM(aH[1][0], bf, acc[S1][0][wt]);
                    acc[S1][1][wt] = MM(aH[1][1], bf, acc[S1][1][wt]);
                }
                if constexpr (K2) {
                    constexpr int S2 = (SM + 1) % 3;
                    acc[S2][0][wt] = MM(aH[2][0], bf, acc[S2][0][wt]);
                    acc[S2][1][wt] = MM(aH[2][1], bf, acc[S2][1][wt]);
                }
            }
            if constexpr (K2) {                      // retire depth S-2 (pk_min)
                constexpr int S2 = (SM + 1) % 3;
#pragma unroll
                for (int cht = 0; cht < 2; ++cht)
#pragma unroll
                    for (int wt = 0; wt < 2; ++wt)
                        mn[cht][wt] = __builtin_elementwise_min(mn[cht][wt],
                                                                acc[S2][cht][wt]);
            }
        }
    };

#define STEP(S) step(std::integral_constant<int, S>{})
    STEP(0);  STEP(1);  STEP(2);  STEP(3);  STEP(4);  STEP(5);  STEP(6);  STEP(7);
    STEP(8);  STEP(9);  STEP(10); STEP(11); STEP(12); STEP(13); STEP(14); STEP(15);
    STEP(16); STEP(17); STEP(18); STEP(19); STEP(20); STEP(21); STEP(22); STEP(23);
    STEP(24); STEP(25); STEP(26); STEP(27); STEP(28); STEP(29); STEP(30); STEP(31);
#undef STEP

    // ---- bias + softmax over channels (lanes m, m+16, m+32, m+48 hold one column)
    {
#pragma unroll
        for (int wt = 0; wt < 2; ++wt) {
            float vals[8];
            float mx = -FLT_MAX;
#pragma unroll
            for (int cht = 0; cht < 2; ++cht)
#pragma unroll
                for (int r = 0; r < 4; ++r) {
                    int c  = cht * 16 + 4 * g + r;
                    int cc = (c < 24) ? c : 0;       // guard OOB bias load
                    float val = mn[cht][wt][r] + bias[cc];
                    if (c >= 24) val = -FLT_MAX;
                    vals[cht * 4 + r] = val;
                    mx = fmaxf(mx, val);
                }
            mx = fmaxf(mx, __shfl_xor(mx, 16));
            mx = fmaxf(mx, __shfl_xor(mx, 32));
            float sum = 0.f;
#pragma unroll
            for (int jj = 0; jj < 8; ++jj) {
                float e = (vals[jj] > -FLT_MAX * 0.5f) ? expf(vals[jj] - mx) : 0.f;
                vals[jj] = e;
                sum += e;
            }
            sum += __shfl_xor(sum, 16);
            sum += __shfl_xor(sum, 32);
            const float inv = 1.0f / sum;
            const int w = wt * 14 + m;               // wt0: 0..15; wt1: 16..29 (m>=2)
            if (wt == 0 || m >= 2) {
#pragma unroll
                for (int cht = 0; cht < 2; ++cht)
#pragma unroll
                    for (int r = 0; r < 4; ++r) {
                        int c = cht * 16 + 4 * g + r;
                        if (c < 24)
                            out[((size_t)(n * 24 + c) * 30 + h) * 30 + w]
                                = vals[cht * 4 + r] * inv;
                    }
            }
        }
    }
}

extern "C" void kernel_launch(void* const* d_in, const int* in_sizes, int n_in,
                              void* d_out, int out_size, void* d_ws, size_t ws_size,
                              hipStream_t stream) {
    const float* x    = (const float*)d_in[0];
    const float* wgt  = (const float*)d_in[1];
    const float* bias = (const float*)d_in[2];
    prep_weights<<<6, 256, 0, stream>>>(wgt, (unsigned*)d_ws);      // 6144 B of d_ws
    conv_mfma<<<N_BATCH * 15, 128, 0, stream>>>(x, (const char*)d_ws, bias, (float*)d_out);
}

// Round 17
// 429.745 us; speedup vs baseline: 1.4275x; 1.4275x over previous
//
#include <hip/hip_runtime.h>
#include <math.h>
#include <float.h>
#include <type_traits>

typedef _Float16 f16x8 __attribute__((ext_vector_type(8)));
typedef _Float16 f16x2 __attribute__((ext_vector_type(2)));
typedef _Float16 f16x4 __attribute__((ext_vector_type(4)));
typedef __fp16   h16x2 __attribute__((ext_vector_type(2)));   // cvt_pkrtz return type
typedef float    f32x4 __attribute__((ext_vector_type(4)));

#define N_BATCH 256

// Tap->slot table (r14-verified conflict-engineered permutation; wid-invariant
// bank windows). Slots j0,j1 / j2,j3 = phases of pair-reads RP1/RP2 (delta 128
// dwords = ci -> ci+1 at 4-row slices); j4..j7 = singles. t = 9*ci+3*kh+kw;
// negative = pad (bank class -t, A weight 0); -1 = pure zero slot.
#define TAP_TABLE                                            \
    { { 0,  9,  2, 11, 18, 20, 22,  4},   /* g0 */           \
      { 6, 15,  8, 17, 24, 26,-25, 13},   /* g1 */           \
      { 1, 10,  3, 12, 19, 21, 23,  5},   /* g2 */           \
      { 7, 16,-24, -1, 25,-24,-26, 14} }  /* g3 */

static __device__ __forceinline__ f32x4 MM(f16x8 a, f16x8 b, f32x4 c) {
    return __builtin_amdgcn_mfma_f32_16x16x32_f16(a, b, c, 0, 0, 0);
}
static __device__ __forceinline__ f16x2 pkrtz(float a, float b) {
    h16x2 r = __builtin_amdgcn_cvt_pkrtz(a, b);
    return __builtin_bit_cast(f16x2, r);
}

// A-fragments (fp16 RTN): set f = kd*2 + cht (6 sets); dword i = f*256 + lane*4 + r.
// Lane l holds A[ch = cht*16 + (l&15)][slot (g=l>>4, j=2r+half)] = weight of tap
// TAP[g][j] (0 for pads). Must match the kernel's B-side gather.
__global__ void prep_weights(const float* __restrict__ w, unsigned* __restrict__ ws) {
    static constexpr int TAP[4][8] = TAP_TABLE;
    int i = blockIdx.x * 256 + threadIdx.x;          // 1536 dwords
    if (i >= 1536) return;
    int f = i >> 8, rem = i & 255;
    int lane = rem >> 2, r = rem & 3;
    int kd = f >> 1, cht = f & 1;
    int g = lane >> 4, chl = lane & 15;
    int ch = cht * 16 + chl;
    unsigned outv = 0;
    for (int half = 0; half < 2; ++half) {
        int t = TAP[g][2 * r + half];
        unsigned short bits = 0;                     // exact zero for pad slots
        if (ch < 24 && t >= 0) {
            int ci = t / 9, rr = t % 9, kh = rr / 3, kw = rr % 3;
            union { _Float16 h; unsigned short u; } cv;
            cv.h = (_Float16)w[(((ch * 3 + ci) * 3 + kd) * 3 + kh) * 3 + kw];
            bits = cv.u;
        }
        outv |= (unsigned)bits << (16 * half);
    }
    ws[i] = outv;
}

__global__ __launch_bounds__(128, 4) void conv_mfma(
    const float* __restrict__ x, const char* __restrict__ wsp,
    const float* __restrict__ bias, float* __restrict__ out)
{
    static constexpr int TAP[4][8] = TAP_TABLE;
    // 5-slot ring of SHARED slices: [slot][ci 0..2][row 0..3][col 0..31], row-rotated
    __shared__ __align__(16) float xs[5 * 384];      // 7680 B

    const int tid  = threadIdx.x;                    // 0..127, 2 waves
    const int lane = tid & 63;
    const int wid  = tid >> 6;                       // 0..1
    const int g = lane >> 4, m = lane & 15;
    // XCD-bijective swizzle (3840 % 8 == 0): XCD k owns n in [32k, 32k+32)
    const int lb = (blockIdx.x & 7) * 480 + (blockIdx.x >> 3);
    const int n  = lb / 15;
    const int h0 = (lb - n * 15) * 2;                // h-tile base: 0,2,...,28
    const int h  = h0 + wid;                         // 0..29, always valid

    // ---- staging: wave0 -> ci0,ci1 (64 lanes); wave1 -> ci2 (lanes<32).
    // Rows h0..h0+3 <= 31 always. Pre-rotated source cols (rot = 8*(row&3)).
    const int ciS  = (wid == 0) ? (lane >> 5) : 2;
    const int rS   = (lane >> 3) & 3;                // slot row 0..3
    const int c4S  = (lane & 7) * 4;
    const int colS = (c4S - 8 * rS) & 31;            // 4-blocks never wrap
    const bool sAct = (wid == 0) || (lane < 32);
    const char* gsb = (const char*)(x + ((size_t)(n * 3 + ciS) * 32768
                                          + (size_t)(h0 + rS) * 32 + colS));

    auto stageTo = [&](int slotFl, int s) {          // one DMA instr per wave
        if (sAct)
            __builtin_amdgcn_global_load_lds(
                (const __attribute__((address_space(1))) unsigned*)(gsb + (size_t)s * 4096),
                (__attribute__((address_space(3))) unsigned*)(xs + slotFl + wid * 256),
                16, 0, 0);
    };

    // ---- gather addresses: byte offset within a slot for tap t (wt variant)
    auto mkidx = [&](int t, int wt) -> unsigned {
        if (t >= 0) {
            int ci = t / 9, rr = t % 9, kh = rr / 3, kw = rr % 3;
            int row = wid + kh;                      // 0..3
            int col = (m + wt * 14 + kw + 8 * (row & 3)) & 31;
            return (unsigned)((ci * 128 + row * 32 + col) * 4);
        } else {                                     // pad: engineered bank class
            int V = -t;                              // 24..26
            int col = (m + wt * 14 + V + 8 * (wid & 3)) & 31;
            return (unsigned)((wid * 32 + col) * 4); // row<=1 of ci0: staged, finite
        }
    };
    unsigned bp[2][2], apoS[2][4];
#pragma unroll
    for (int wt = 0; wt < 2; ++wt) {
        bp[wt][0] = mkidx(TAP[g][0], wt);            // RP1 base (phase1 = +128 dwords)
        bp[wt][1] = mkidx(TAP[g][2], wt);            // RP2 base
#pragma unroll
        for (int j = 0; j < 4; ++j) apoS[wt][j] = mkidx(TAP[g][4 + j], wt);
    }

    // ---- preload 6 A-fragments (loop-invariant, 24 VGPRs)
    const char* wl = wsp + (size_t)lane * 16;
    f16x8 aH[3][2];
#pragma unroll
    for (int kd = 0; kd < 3; ++kd)
#pragma unroll
        for (int cht = 0; cht < 2; ++cht)
            aH[kd][cht] = *(const f16x8*)(wl + (size_t)(kd * 2 + cht) * 1024);

    f32x4 acc[3][2][2];                              // [depth%3][cht][wt]; fresh at kd=0
    f32x4 mn[2][2];
#pragma unroll
    for (int b = 0; b < 2; ++b)
#pragma unroll
        for (int c = 0; c < 2; ++c) mn[b][c] = (f32x4){FLT_MAX, FLT_MAX, FLT_MAX, FLT_MAX};
    const f32x4 ZR = (f32x4){0.f, 0.f, 0.f, 0.f};

    stageTo(0, 0); stageTo(384, 1); stageTo(768, 2); stageTo(1152, 3);  // 3-deep prologue

    const char* xb = (const char*)xs;

    auto step = [&](auto sc) {
        constexpr int  S    = decltype(sc)::value;
        constexpr int  SLOT = (S % 5) * 1536;        // byte offset of slice S
        constexpr int  SM   = S % 3;
        constexpr bool K0 = (S <= 29), K1 = (S >= 1 && S <= 30), K2 = (S >= 2);

        // drain own DMA for slice S; keep 3 youngest prefetches in flight
        if constexpr (S <= 28)      asm volatile("s_waitcnt vmcnt(3)\ns_barrier" ::: "memory");
        else if constexpr (S == 29) asm volatile("s_waitcnt vmcnt(2)\ns_barrier" ::: "memory");
        else if constexpr (S == 30) asm volatile("s_waitcnt vmcnt(1)\ns_barrier" ::: "memory");
        else                        asm volatile("s_waitcnt vmcnt(0)\ns_barrier" ::: "memory");
        if constexpr (S + 4 <= 31) stageTo(((S + 4) % 5) * 384, S + 4);  // retired slot
        __builtin_amdgcn_sched_barrier(0);

        {
#pragma unroll
            for (int wt = 0; wt < 2; ++wt) {
                float xv[8];
                // pair reads: ds_read2_b32 offset0:0 offset1:128 (delta ci->ci+1)
                const float* q0 = (const float*)(xb + SLOT + bp[wt][0]);
                xv[0] = q0[0]; xv[1] = q0[128];
                const float* q1 = (const float*)(xb + SLOT + bp[wt][1]);
                xv[2] = q1[0]; xv[3] = q1[128];
#pragma unroll
                for (int j = 0; j < 4; ++j)          // singles (imm-offset b32)
                    xv[4 + j] = *(const float*)(xb + SLOT + apoS[wt][j]);
                f16x2 p0 = pkrtz(xv[0], xv[1]);
                f16x2 p1 = pkrtz(xv[2], xv[3]);
                f16x2 p2 = pkrtz(xv[4], xv[5]);
                f16x2 p3 = pkrtz(xv[6], xv[7]);
                f16x4 lo = __builtin_shufflevector(p0, p1, 0, 1, 2, 3);
                f16x4 hi = __builtin_shufflevector(p2, p3, 0, 1, 2, 3);
                f16x8 bf = __builtin_shufflevector(lo, hi, 0, 1, 2, 3, 4, 5, 6, 7);
                if constexpr (K0) {                  // fresh depth S from zero C
                    acc[SM][0][wt] = MM(aH[0][0], bf, ZR);
                    acc[SM][1][wt] = MM(aH[0][1], bf, ZR);
                }
                if constexpr (K1) {
                    constexpr int S1 = (SM + 2) % 3;
                    acc[S1][0][wt] = MM(aH[1][0], bf, acc[S1][0][wt]);
                    acc[S1][1][wt] = MM(aH[1][1], bf, acc[S1][1][wt]);
                }
                if constexpr (K2) {
                    constexpr int S2 = (SM + 1) % 3;
                    acc[S2][0][wt] = MM(aH[2][0], bf, acc[S2][0][wt]);
                    acc[S2][1][wt] = MM(aH[2][1], bf, acc[S2][1][wt]);
                }
            }
            if constexpr (K2) {                      // retire depth S-2 (pk_min)
                constexpr int S2 = (SM + 1) % 3;
#pragma unroll
                for (int cht = 0; cht < 2; ++cht)
#pragma unroll
                    for (int wt = 0; wt < 2; ++wt)
                        mn[cht][wt] = __builtin_elementwise_min(mn[cht][wt],
                                                                acc[S2][cht][wt]);
            }
        }
    };

#define STEP(S) step(std::integral_constant<int, S>{})
    STEP(0);  STEP(1);  STEP(2);  STEP(3);  STEP(4);  STEP(5);  STEP(6);  STEP(7);
    STEP(8);  STEP(9);  STEP(10); STEP(11); STEP(12); STEP(13); STEP(14); STEP(15);
    STEP(16); STEP(17); STEP(18); STEP(19); STEP(20); STEP(21); STEP(22); STEP(23);
    STEP(24); STEP(25); STEP(26); STEP(27); STEP(28); STEP(29); STEP(30); STEP(31);
#undef STEP

    // ---- bias + softmax over channels (lanes m, m+16, m+32, m+48 hold one column)
    {
#pragma unroll
        for (int wt = 0; wt < 2; ++wt) {
            float vals[8];
            float mx = -FLT_MAX;
#pragma unroll
            for (int cht = 0; cht < 2; ++cht)
#pragma unroll
                for (int r = 0; r < 4; ++r) {
                    int c  = cht * 16 + 4 * g + r;
                    int cc = (c < 24) ? c : 0;       // guard OOB bias load
                    float val = mn[cht][wt][r] + bias[cc];
                    if (c >= 24) val = -FLT_MAX;
                    vals[cht * 4 + r] = val;
                    mx = fmaxf(mx, val);
                }
            mx = fmaxf(mx, __shfl_xor(mx, 16));
            mx = fmaxf(mx, __shfl_xor(mx, 32));
            float sum = 0.f;
#pragma unroll
            for (int jj = 0; jj < 8; ++jj) {
                float e = (vals[jj] > -FLT_MAX * 0.5f) ? expf(vals[jj] - mx) : 0.f;
                vals[jj] = e;
                sum += e;
            }
            sum += __shfl_xor(sum, 16);
            sum += __shfl_xor(sum, 32);
            const float inv = 1.0f / sum;
            const int w = wt * 14 + m;               // wt0: 0..15; wt1: 16..29 (m>=2)
            if (wt == 0 || m >= 2) {
#pragma unroll
                for (int cht = 0; cht < 2; ++cht)
#pragma unroll
                    for (int r = 0; r < 4; ++r) {
                        int c = cht * 16 + 4 * g + r;
                        if (c < 24)
                            out[((size_t)(n * 24 + c) * 30 + h) * 30 + w]
                                = vals[cht * 4 + r] * inv;
                    }
            }
        }
    }
}

extern "C" void kernel_launch(void* const* d_in, const int* in_sizes, int n_in,
                              void* d_out, int out_size, void* d_ws, size_t ws_size,
                              hipStream_t stream) {
    const float* x    = (const float*)d_in[0];
    const float* wgt  = (const float*)d_in[1];
    const float* bias = (const float*)d_in[2];
    prep_weights<<<6, 256, 0, stream>>>(wgt, (unsigned*)d_ws);      // 6144 B of d_ws
    conv_mfma<<<N_BATCH * 15, 128, 0, stream>>>(x, (const char*)d_ws, bias, (float*)d_out);
}

// Round 18
// 371.669 us; speedup vs baseline: 1.6506x; 1.1563x over previous
//
#include <hip/hip_runtime.h>
#include <math.h>
#include <float.h>
#include <type_traits>

typedef _Float16 f16x8 __attribute__((ext_vector_type(8)));
typedef _Float16 f16x2 __attribute__((ext_vector_type(2)));
typedef _Float16 f16x4 __attribute__((ext_vector_type(4)));
typedef __fp16   h16x2 __attribute__((ext_vector_type(2)));   // cvt_pkrtz return type
typedef float    f32x4 __attribute__((ext_vector_type(4)));

#define N_BATCH 256

// Tap->slot table (r14-verified conflict-engineered permutation; wid-invariant
// bank windows). Slots j0,j1 / j2,j3 = phases of pair-reads RP1/RP2 (delta 128
// dwords = ci -> ci+1 at 4-row slices); j4..j7 = singles. t = 9*ci+3*kh+kw;
// negative = pad (bank class -t, A weight 0); -1 = pure zero slot.
#define TAP_TABLE                                            \
    { { 0,  9,  2, 11, 18, 20, 22,  4},   /* g0 */           \
      { 6, 15,  8, 17, 24, 26,-25, 13},   /* g1 */           \
      { 1, 10,  3, 12, 19, 21, 23,  5},   /* g2 */           \
      { 7, 16,-24, -1, 25,-24,-26, 14} }  /* g3 */

static __device__ __forceinline__ f32x4 MM(f16x8 a, f16x8 b, f32x4 c) {
    return __builtin_amdgcn_mfma_f32_16x16x32_f16(a, b, c, 0, 0, 0);
}
static __device__ __forceinline__ f16x2 pkrtz(float a, float b) {
    h16x2 r = __builtin_amdgcn_cvt_pkrtz(a, b);
    return __builtin_bit_cast(f16x2, r);
}

// A-fragments (fp16 RTN): set f = kd*2 + cht (6 sets); dword i = f*256 + lane*4 + r.
// Lane l holds A[ch = cht*16 + (l&15)][slot (g=l>>4, j=2r+half)] = weight of tap
// TAP[g][j] (0 for pads). Must match the kernel's B-side gather.
__global__ void prep_weights(const float* __restrict__ w, unsigned* __restrict__ ws) {
    static constexpr int TAP[4][8] = TAP_TABLE;
    int i = blockIdx.x * 256 + threadIdx.x;          // 1536 dwords
    if (i >= 1536) return;
    int f = i >> 8, rem = i & 255;
    int lane = rem >> 2, r = rem & 3;
    int kd = f >> 1, cht = f & 1;
    int g = lane >> 4, chl = lane & 15;
    int ch = cht * 16 + chl;
    unsigned outv = 0;
    for (int half = 0; half < 2; ++half) {
        int t = TAP[g][2 * r + half];
        unsigned short bits = 0;                     // exact zero for pad slots
        if (ch < 24 && t >= 0) {
            int ci = t / 9, rr = t % 9, kh = rr / 3, kw = rr % 3;
            union { _Float16 h; unsigned short u; } cv;
            cv.h = (_Float16)w[(((ch * 3 + ci) * 3 + kd) * 3 + kh) * 3 + kw];
            bits = cv.u;
        }
        outv |= (unsigned)bits << (16 * half);
    }
    ws[i] = outv;
}

__global__ __launch_bounds__(128, 3) void conv_mfma(
    const float* __restrict__ x, const char* __restrict__ wsp,
    const float* __restrict__ bias, float* __restrict__ out)
{
    static constexpr int TAP[4][8] = TAP_TABLE;
    // 5-slot ring of SHARED slices: [slot][ci 0..2][row 0..3][col 0..31], row-rotated
    __shared__ __align__(16) float xs[5 * 384];      // 7680 B

    const int tid  = threadIdx.x;                    // 0..127, 2 waves
    const int lane = tid & 63;
    const int wid  = tid >> 6;                       // 0..1
    const int g = lane >> 4, m = lane & 15;
    // XCD-bijective swizzle (3840 % 8 == 0): XCD k owns n in [32k, 32k+32)
    const int lb = (blockIdx.x & 7) * 480 + (blockIdx.x >> 3);
    const int n  = lb / 15;
    const int h0 = (lb - n * 15) * 2;                // h-tile base: 0,2,...,28
    const int h  = h0 + wid;                         // 0..29, always valid

    // ---- staging: wave0 -> ci0,ci1 (64 lanes); wave1 -> ci2 (lanes<32).
    // Rows h0..h0+3 <= 31 always. Pre-rotated source cols (rot = 8*(row&3)).
    const int ciS  = (wid == 0) ? (lane >> 5) : 2;
    const int rS   = (lane >> 3) & 3;                // slot row 0..3
    const int c4S  = (lane & 7) * 4;
    const int colS = (c4S - 8 * rS) & 31;            // 4-blocks never wrap
    const bool sAct = (wid == 0) || (lane < 32);
    const char* gsb = (const char*)(x + ((size_t)(n * 3 + ciS) * 32768
                                          + (size_t)(h0 + rS) * 32 + colS));

    auto stageTo = [&](int slotFl, int s) {          // one DMA instr per wave
        if (sAct)
            __builtin_amdgcn_global_load_lds(
                (const __attribute__((address_space(1))) unsigned*)(gsb + (size_t)s * 4096),
                (__attribute__((address_space(3))) unsigned*)(xs + slotFl + wid * 256),
                16, 0, 0);
    };

    // ---- gather addresses: byte offset within a slot for tap t (wt variant)
    auto mkidx = [&](int t, int wt) -> unsigned {
        if (t >= 0) {
            int ci = t / 9, rr = t % 9, kh = rr / 3, kw = rr % 3;
            int row = wid + kh;                      // 0..3
            int col = (m + wt * 14 + kw + 8 * (row & 3)) & 31;
            return (unsigned)((ci * 128 + row * 32 + col) * 4);
        } else {                                     // pad: engineered bank class
            int V = -t;                              // 24..26
            int col = (m + wt * 14 + V + 8 * (wid & 3)) & 31;
            return (unsigned)((wid * 32 + col) * 4); // row<=1 of ci0: staged, finite
        }
    };
    unsigned bp[2][2], apoS[2][4];
#pragma unroll
    for (int wt = 0; wt < 2; ++wt) {
        bp[wt][0] = mkidx(TAP[g][0], wt);            // RP1 base (phase1 = +128 dwords)
        bp[wt][1] = mkidx(TAP[g][2], wt);            // RP2 base
#pragma unroll
        for (int j = 0; j < 4; ++j) apoS[wt][j] = mkidx(TAP[g][4 + j], wt);
    }

    // ---- preload 6 A-fragments (loop-invariant, 24 VGPRs)
    const char* wl = wsp + (size_t)lane * 16;
    f16x8 aH[3][2];
#pragma unroll
    for (int kd = 0; kd < 3; ++kd)
#pragma unroll
        for (int cht = 0; cht < 2; ++cht)
            aH[kd][cht] = *(const f16x8*)(wl + (size_t)(kd * 2 + cht) * 1024);

    f32x4 acc[3][2][2];                              // [depth%3][cht][wt]; fresh at kd=0
    f32x4 mn[2][2];
#pragma unroll
    for (int b = 0; b < 2; ++b)
#pragma unroll
        for (int c = 0; c < 2; ++c) mn[b][c] = (f32x4){FLT_MAX, FLT_MAX, FLT_MAX, FLT_MAX};
    const f32x4 ZR = (f32x4){0.f, 0.f, 0.f, 0.f};

    stageTo(0, 0); stageTo(384, 1); stageTo(768, 2); stageTo(1152, 3);  // 3-deep prologue

    const char* xb = (const char*)xs;

    auto step = [&](auto sc) {
        constexpr int  S    = decltype(sc)::value;
        constexpr int  SLOT = (S % 5) * 1536;        // byte offset of slice S
        constexpr int  SM   = S % 3;
        constexpr bool K0 = (S <= 29), K1 = (S >= 1 && S <= 30), K2 = (S >= 2);

        // drain own DMA for slice S; keep 3 youngest prefetches in flight
        if constexpr (S <= 28)      asm volatile("s_waitcnt vmcnt(3)\ns_barrier" ::: "memory");
        else if constexpr (S == 29) asm volatile("s_waitcnt vmcnt(2)\ns_barrier" ::: "memory");
        else if constexpr (S == 30) asm volatile("s_waitcnt vmcnt(1)\ns_barrier" ::: "memory");
        else                        asm volatile("s_waitcnt vmcnt(0)\ns_barrier" ::: "memory");
        if constexpr (S + 4 <= 31) stageTo(((S + 4) % 5) * 384, S + 4);  // retired slot
        __builtin_amdgcn_sched_barrier(0);

        {
#pragma unroll
            for (int wt = 0; wt < 2; ++wt) {
                float xv[8];
                // pair reads: ds_read2_b32 offset0:0 offset1:128 (delta ci->ci+1)
                const float* q0 = (const float*)(xb + SLOT + bp[wt][0]);
                xv[0] = q0[0]; xv[1] = q0[128];
                const float* q1 = (const float*)(xb + SLOT + bp[wt][1]);
                xv[2] = q1[0]; xv[3] = q1[128];
#pragma unroll
                for (int j = 0; j < 4; ++j)          // singles (imm-offset b32)
                    xv[4 + j] = *(const float*)(xb + SLOT + apoS[wt][j]);
                f16x2 p0 = pkrtz(xv[0], xv[1]);
                f16x2 p1 = pkrtz(xv[2], xv[3]);
                f16x2 p2 = pkrtz(xv[4], xv[5]);
                f16x2 p3 = pkrtz(xv[6], xv[7]);
                f16x4 lo = __builtin_shufflevector(p0, p1, 0, 1, 2, 3);
                f16x4 hi = __builtin_shufflevector(p2, p3, 0, 1, 2, 3);
                f16x8 bf = __builtin_shufflevector(lo, hi, 0, 1, 2, 3, 4, 5, 6, 7);
                if constexpr (K0) {                  // fresh depth S from zero C
                    acc[SM][0][wt] = MM(aH[0][0], bf, ZR);
                    acc[SM][1][wt] = MM(aH[0][1], bf, ZR);
                }
                if constexpr (K1) {
                    constexpr int S1 = (SM + 2) % 3;
                    acc[S1][0][wt] = MM(aH[1][0], bf, acc[S1][0][wt]);
                    acc[S1][1][wt] = MM(aH[1][1], bf, acc[S1][1][wt]);
                }
                if constexpr (K2) {
                    constexpr int S2 = (SM + 1) % 3;
                    acc[S2][0][wt] = MM(aH[2][0], bf, acc[S2][0][wt]);
                    acc[S2][1][wt] = MM(aH[2][1], bf, acc[S2][1][wt]);
                }
            }
            if constexpr (K2) {                      // retire depth S-2 (pk_min)
                constexpr int S2 = (SM + 1) % 3;
#pragma unroll
                for (int cht = 0; cht < 2; ++cht)
#pragma unroll
                    for (int wt = 0; wt < 2; ++wt)
                        mn[cht][wt] = __builtin_elementwise_min(mn[cht][wt],
                                                                acc[S2][cht][wt]);
            }
        }
    };

#define STEP(S) step(std::integral_constant<int, S>{})
    STEP(0);  STEP(1);  STEP(2);  STEP(3);  STEP(4);  STEP(5);  STEP(6);  STEP(7);
    STEP(8);  STEP(9);  STEP(10); STEP(11); STEP(12); STEP(13); STEP(14); STEP(15);
    STEP(16); STEP(17); STEP(18); STEP(19); STEP(20); STEP(21); STEP(22); STEP(23);
    STEP(24); STEP(25); STEP(26); STEP(27); STEP(28); STEP(29); STEP(30); STEP(31);
#undef STEP

    // ---- bias + softmax over channels (lanes m, m+16, m+32, m+48 hold one column)
    {
#pragma unroll
        for (int wt = 0; wt < 2; ++wt) {
            float vals[8];
            float mx = -FLT_MAX;
#pragma unroll
            for (int cht = 0; cht < 2; ++cht)
#pragma unroll
                for (int r = 0; r < 4; ++r) {
                    int c  = cht * 16 + 4 * g + r;
                    int cc = (c < 24) ? c : 0;       // guard OOB bias load
                    float val = mn[cht][wt][r] + bias[cc];
                    if (c >= 24) val = -FLT_MAX;
                    vals[cht * 4 + r] = val;
                    mx = fmaxf(mx, val);
                }
            mx = fmaxf(mx, __shfl_xor(mx, 16));
            mx = fmaxf(mx, __shfl_xor(mx, 32));
            float sum = 0.f;
#pragma unroll
            for (int jj = 0; jj < 8; ++jj) {
                float e = (vals[jj] > -FLT_MAX * 0.5f) ? expf(vals[jj] - mx) : 0.f;
                vals[jj] = e;
                sum += e;
            }
            sum += __shfl_xor(sum, 16);
            sum += __shfl_xor(sum, 32);
            const float inv = 1.0f / sum;
            const int w = wt * 14 + m;               // wt0: 0..15; wt1: 16..29 (m>=2)
            if (wt == 0 || m >= 2) {
#pragma unroll
                for (int cht = 0; cht < 2; ++cht)
#pragma unroll
                    for (int r = 0; r < 4; ++r) {
                        int c = cht * 16 + 4 * g + r;
                        if (c < 24)
                            out[((size_t)(n * 24 + c) * 30 + h) * 30 + w]
                                = vals[cht * 4 + r] * inv;
                    }
            }
        }
    }
}

extern "C" void kernel_launch(void* const* d_in, const int* in_sizes, int n_in,
                              void* d_out, int out_size, void* d_ws, size_t ws_size,
                              hipStream_t stream) {
    const float* x    = (const float*)d_in[0];
    const float* wgt  = (const float*)d_in[1];
    const float* bias = (const float*)d_in[2];
    prep_weights<<<6, 256, 0, stream>>>(wgt, (unsigned*)d_ws);      // 6144 B of d_ws
    conv_mfma<<<N_BATCH * 15, 128, 0, stream>>>(x, (const char*)d_ws, bias, (float*)d_out);
}

// Round 19
// 140.392 us; speedup vs baseline: 4.3697x; 2.6474x over previous
//
#include <hip/hip_runtime.h>
#include <math.h>
#include <float.h>
#include <type_traits>

typedef _Float16 f16x8 __attribute__((ext_vector_type(8)));
typedef _Float16 f16x2 __attribute__((ext_vector_type(2)));
typedef _Float16 f16x4 __attribute__((ext_vector_type(4)));
typedef __fp16   h16x2 __attribute__((ext_vector_type(2)));   // cvt_pkrtz return type
typedef float    f32x4 __attribute__((ext_vector_type(4)));

#define N_BATCH 256

// Tap->slot table (r14-verified conflict-engineered permutation; wid-invariant
// bank windows). Slots j0,j1 / j2,j3 = phases of pair-reads RP1/RP2 (delta 128
// dwords = ci -> ci+1 at 4-row slices); j4..j7 = singles. t = 9*ci+3*kh+kw;
// negative = pad (bank class -t, A weight 0); -1 = pure zero slot.
#define TAP_TABLE                                            \
    { { 0,  9,  2, 11, 18, 20, 22,  4},   /* g0 */           \
      { 6, 15,  8, 17, 24, 26,-25, 13},   /* g1 */           \
      { 1, 10,  3, 12, 19, 21, 23,  5},   /* g2 */           \
      { 7, 16,-24, -1, 25,-24,-26, 14} }  /* g3 */

static __device__ __forceinline__ f32x4 MM(f16x8 a, f16x8 b, f32x4 c) {
    return __builtin_amdgcn_mfma_f32_16x16x32_f16(a, b, c, 0, 0, 0);
}
static __device__ __forceinline__ f16x2 pkrtz(float a, float b) {
    h16x2 r = __builtin_amdgcn_cvt_pkrtz(a, b);
    return __builtin_bit_cast(f16x2, r);
}

// A-fragments (fp16 RTN): set f = kd*2 + cht (6 sets); dword i = f*256 + lane*4 + r.
// Lane l holds A[ch = cht*16 + (l&15)][slot (g=l>>4, j=2r+half)] = weight of tap
// TAP[g][j] (0 for pads). Must match the kernel's B-side gather.
__global__ void prep_weights(const float* __restrict__ w, unsigned* __restrict__ ws) {
    static constexpr int TAP[4][8] = TAP_TABLE;
    int i = blockIdx.x * 256 + threadIdx.x;          // 1536 dwords
    if (i >= 1536) return;
    int f = i >> 8, rem = i & 255;
    int lane = rem >> 2, r = rem & 3;
    int kd = f >> 1, cht = f & 1;
    int g = lane >> 4, chl = lane & 15;
    int ch = cht * 16 + chl;
    unsigned outv = 0;
    for (int half = 0; half < 2; ++half) {
        int t = TAP[g][2 * r + half];
        unsigned short bits = 0;                     // exact zero for pad slots
        if (ch < 24 && t >= 0) {
            int ci = t / 9, rr = t % 9, kh = rr / 3, kw = rr % 3;
            union { _Float16 h; unsigned short u; } cv;
            cv.h = (_Float16)w[(((ch * 3 + ci) * 3 + kd) * 3 + kh) * 3 + kw];
            bits = cv.u;
        }
        outv |= (unsigned)bits << (16 * half);
    }
    ws[i] = outv;
}

__global__ __launch_bounds__(128) void conv_mfma(
    const float* __restrict__ x, const char* __restrict__ wsp,
    const float* __restrict__ bias, float* __restrict__ out)
{
    static constexpr int TAP[4][8] = TAP_TABLE;
    // 5-slot ring of SHARED slices: [slot][ci 0..2][row 0..3][col 0..31], row-rotated
    __shared__ __align__(16) float xs[5 * 384];      // 7680 B

    const int tid  = threadIdx.x;                    // 0..127, 2 waves
    const int lane = tid & 63;
    const int wid  = tid >> 6;                       // 0..1
    const int g = lane >> 4, m = lane & 15;
    // XCD-bijective swizzle (3840 % 8 == 0): XCD k owns n in [32k, 32k+32)
    const int lb = (blockIdx.x & 7) * 480 + (blockIdx.x >> 3);
    const int n  = lb / 15;
    const int h0 = (lb - n * 15) * 2;                // h-tile base: 0,2,...,28
    const int h  = h0 + wid;                         // 0..29, always valid

    // ---- staging: wave0 -> ci0,ci1 (64 lanes); wave1 -> ci2 (lanes<32).
    // Rows h0..h0+3 <= 31 always. Pre-rotated source cols (rot = 8*(row&3)).
    const int ciS  = (wid == 0) ? (lane >> 5) : 2;
    const int rS   = (lane >> 3) & 3;                // slot row 0..3
    const int c4S  = (lane & 7) * 4;
    const int colS = (c4S - 8 * rS) & 31;            // 4-blocks never wrap
    const bool sAct = (wid == 0) || (lane < 32);
    const char* gsb = (const char*)(x + ((size_t)(n * 3 + ciS) * 32768
                                          + (size_t)(h0 + rS) * 32 + colS));

    auto stageTo = [&](int slotFl, int s) {          // one DMA instr per wave
        if (sAct)
            __builtin_amdgcn_global_load_lds(
                (const __attribute__((address_space(1))) unsigned*)(gsb + (size_t)s * 4096),
                (__attribute__((address_space(3))) unsigned*)(xs + slotFl + wid * 256),
                16, 0, 0);
    };

    // ---- gather addresses: byte offset within a slot for tap t (wt variant)
    auto mkidx = [&](int t, int wt) -> unsigned {
        if (t >= 0) {
            int ci = t / 9, rr = t % 9, kh = rr / 3, kw = rr % 3;
            int row = wid + kh;                      // 0..3
            int col = (m + wt * 14 + kw + 8 * (row & 3)) & 31;
            return (unsigned)((ci * 128 + row * 32 + col) * 4);
        } else {                                     // pad: engineered bank class
            int V = -t;                              // 24..26
            int col = (m + wt * 14 + V + 8 * (wid & 3)) & 31;
            return (unsigned)((wid * 32 + col) * 4); // row<=1 of ci0: staged, finite
        }
    };
    unsigned bp[2][2], apoS[2][4];
#pragma unroll
    for (int wt = 0; wt < 2; ++wt) {
        bp[wt][0] = mkidx(TAP[g][0], wt);            // RP1 base (phase1 = +128 dwords)
        bp[wt][1] = mkidx(TAP[g][2], wt);            // RP2 base
#pragma unroll
        for (int j = 0; j < 4; ++j) apoS[wt][j] = mkidx(TAP[g][4 + j], wt);
    }

    // ---- preload 6 A-fragments (loop-invariant, 24 VGPRs)
    const char* wl = wsp + (size_t)lane * 16;
    f16x8 aH[3][2];
#pragma unroll
    for (int kd = 0; kd < 3; ++kd)
#pragma unroll
        for (int cht = 0; cht < 2; ++cht)
            aH[kd][cht] = *(const f16x8*)(wl + (size_t)(kd * 2 + cht) * 1024);

    f32x4 acc[3][2][2];                              // [depth%3][cht][wt]; fresh at kd=0
    f32x4 mn[2][2];
#pragma unroll
    for (int b = 0; b < 2; ++b)
#pragma unroll
        for (int c = 0; c < 2; ++c) mn[b][c] = (f32x4){FLT_MAX, FLT_MAX, FLT_MAX, FLT_MAX};
    const f32x4 ZR = (f32x4){0.f, 0.f, 0.f, 0.f};

    stageTo(0, 0); stageTo(384, 1); stageTo(768, 2); stageTo(1152, 3);  // 3-deep prologue

    const char* xb = (const char*)xs;

    auto step = [&](auto sc) {
        constexpr int  S    = decltype(sc)::value;
        constexpr int  SLOT = (S % 5) * 1536;        // byte offset of slice S
        constexpr int  SM   = S % 3;
        constexpr bool K0 = (S <= 29), K1 = (S >= 1 && S <= 30), K2 = (S >= 2);

        // drain own DMA for slice S; keep 3 youngest prefetches in flight
        if constexpr (S <= 28)      asm volatile("s_waitcnt vmcnt(3)\ns_barrier" ::: "memory");
        else if constexpr (S == 29) asm volatile("s_waitcnt vmcnt(2)\ns_barrier" ::: "memory");
        else if constexpr (S == 30) asm volatile("s_waitcnt vmcnt(1)\ns_barrier" ::: "memory");
        else                        asm volatile("s_waitcnt vmcnt(0)\ns_barrier" ::: "memory");
        if constexpr (S + 4 <= 31) stageTo(((S + 4) % 5) * 384, S + 4);  // retired slot
        __builtin_amdgcn_sched_barrier(0);

        {
#pragma unroll
            for (int wt = 0; wt < 2; ++wt) {
                float xv[8];
                // pair reads: ds_read2_b32 offset0:0 offset1:128 (delta ci->ci+1)
                const float* q0 = (const float*)(xb + SLOT + bp[wt][0]);
                xv[0] = q0[0]; xv[1] = q0[128];
                const float* q1 = (const float*)(xb + SLOT + bp[wt][1]);
                xv[2] = q1[0]; xv[3] = q1[128];
#pragma unroll
                for (int j = 0; j < 4; ++j)          // singles (imm-offset b32)
                    xv[4 + j] = *(const float*)(xb + SLOT + apoS[wt][j]);
                f16x2 p0 = pkrtz(xv[0], xv[1]);
                f16x2 p1 = pkrtz(xv[2], xv[3]);
                f16x2 p2 = pkrtz(xv[4], xv[5]);
                f16x2 p3 = pkrtz(xv[6], xv[7]);
                f16x4 lo = __builtin_shufflevector(p0, p1, 0, 1, 2, 3);
                f16x4 hi = __builtin_shufflevector(p2, p3, 0, 1, 2, 3);
                f16x8 bf = __builtin_shufflevector(lo, hi, 0, 1, 2, 3, 4, 5, 6, 7);
                if constexpr (K0) {                  // fresh depth S from zero C
                    acc[SM][0][wt] = MM(aH[0][0], bf, ZR);
                    acc[SM][1][wt] = MM(aH[0][1], bf, ZR);
                }
                if constexpr (K1) {
                    constexpr int S1 = (SM + 2) % 3;
                    acc[S1][0][wt] = MM(aH[1][0], bf, acc[S1][0][wt]);
                    acc[S1][1][wt] = MM(aH[1][1], bf, acc[S1][1][wt]);
                }
                if constexpr (K2) {
                    constexpr int S2 = (SM + 1) % 3;
                    acc[S2][0][wt] = MM(aH[2][0], bf, acc[S2][0][wt]);
                    acc[S2][1][wt] = MM(aH[2][1], bf, acc[S2][1][wt]);
                }
            }
            if constexpr (K2) {                      // retire depth S-2 (pk_min)
                constexpr int S2 = (SM + 1) % 3;
#pragma unroll
                for (int cht = 0; cht < 2; ++cht)
#pragma unroll
                    for (int wt = 0; wt < 2; ++wt)
                        mn[cht][wt] = __builtin_elementwise_min(mn[cht][wt],
                                                                acc[S2][cht][wt]);
            }
        }
    };

#define STEP(S) step(std::integral_constant<int, S>{})
    STEP(0);  STEP(1);  STEP(2);  STEP(3);  STEP(4);  STEP(5);  STEP(6);  STEP(7);
    STEP(8);  STEP(9);  STEP(10); STEP(11); STEP(12); STEP(13); STEP(14); STEP(15);
    STEP(16); STEP(17); STEP(18); STEP(19); STEP(20); STEP(21); STEP(22); STEP(23);
    STEP(24); STEP(25); STEP(26); STEP(27); STEP(28); STEP(29); STEP(30); STEP(31);
#undef STEP

    // ---- bias + softmax over channels (lanes m, m+16, m+32, m+48 hold one column)
    {
#pragma unroll
        for (int wt = 0; wt < 2; ++wt) {
            float vals[8];
            float mx = -FLT_MAX;
#pragma unroll
            for (int cht = 0; cht < 2; ++cht)
#pragma unroll
                for (int r = 0; r < 4; ++r) {
                    int c  = cht * 16 + 4 * g + r;
                    int cc = (c < 24) ? c : 0;       // guard OOB bias load
                    float val = mn[cht][wt][r] + bias[cc];
                    if (c >= 24) val = -FLT_MAX;
                    vals[cht * 4 + r] = val;
                    mx = fmaxf(mx, val);
                }
            mx = fmaxf(mx, __shfl_xor(mx, 16));
            mx = fmaxf(mx, __shfl_xor(mx, 32));
            float sum = 0.f;
#pragma unroll
            for (int jj = 0; jj < 8; ++jj) {
                float e = (vals[jj] > -FLT_MAX * 0.5f) ? expf(vals[jj] - mx) : 0.f;
                vals[jj] = e;
                sum += e;
            }
            sum += __shfl_xor(sum, 16);
            sum += __shfl_xor(sum, 32);
            const float inv = 1.0f / sum;
            const int w = wt * 14 + m;               // wt0: 0..15; wt1: 16..29 (m>=2)
            if (wt == 0 || m >= 2) {
#pragma unroll
                for (int cht = 0; cht < 2; ++cht)
#pragma unroll
                    for (int r = 0; r < 4; ++r) {
                        int c = cht * 16 + 4 * g + r;
                        if (c < 24)
                            out[((size_t)(n * 24 + c) * 30 + h) * 30 + w]
                                = vals[cht * 4 + r] * inv;
                    }
            }
        }
    }
}

extern "C" void kernel_launch(void* const* d_in, const int* in_sizes, int n_in,
                              void* d_out, int out_size, void* d_ws, size_t ws_size,
                              hipStream_t stream) {
    const float* x    = (const float*)d_in[0];
    const float* wgt  = (const float*)d_in[1];
    const float* bias = (const float*)d_in[2];
    prep_weights<<<6, 256, 0, stream>>>(wgt, (unsigned*)d_ws);      // 6144 B of d_ws
    conv_mfma<<<N_BATCH * 15, 128, 0, stream>>>(x, (const char*)d_ws, bias, (float*)d_out);
}

// Round 20
// 63.655 us; speedup vs baseline: 9.6374x; 2.2055x over previous
//
#include <hip/hip_runtime.h>
#include <math.h>
#include <float.h>
#include <type_traits>

typedef _Float16 f16x8 __attribute__((ext_vector_type(8)));
typedef _Float16 f16x2 __attribute__((ext_vector_type(2)));
typedef _Float16 f16x4 __attribute__((ext_vector_type(4)));
typedef __fp16   h16x2 __attribute__((ext_vector_type(2)));   // cvt_pkrtz return type
typedef float    f32x4 __attribute__((ext_vector_type(4)));

#define N_BATCH 256

// Tap->slot table. Slots j0,j1 = phases of pair-read RP1 (ds_read2_b32, delta 192
// dwords = ci -> ci+1); j2,j3 = RP2; j4..j7 = singles S1..S4. Values: tap id
// t = 9*ci+3*kh+kw; negative = pad (B reads bank-class -t; A weight = 0); -1 = pure
// zero slot (phase1 of g3's pad-pair, address implicit). Bank windows per instr:
// RP1 {0,16,1,17}, RP2 {2,18,8,24}, S1 {0,16,1,17}, S2 {2,18,8,24}, S3 {9,25,10,26}
// (all perfect 2-way = free); S4 {9,9,10,10} residual.
#define TAP_TABLE                                            \
    { { 0,  9,  2, 11, 18, 20, 22,  4},   /* g0 */           \
      { 6, 15,  8, 17, 24, 26,-25, 13},   /* g1 */           \
      { 1, 10,  3, 12, 19, 21, 23,  5},   /* g2 */           \
      { 7, 16,-24, -1, 25,-24,-26, 14} }  /* g3 */

static __device__ __forceinline__ f32x4 MM(f16x8 a, f16x8 b, f32x4 c) {
    return __builtin_amdgcn_mfma_f32_16x16x32_f16(a, b, c, 0, 0, 0);
}
static __device__ __forceinline__ f16x2 pkrtz(float a, float b) {
    h16x2 r = __builtin_amdgcn_cvt_pkrtz(a, b);
    return __builtin_bit_cast(f16x2, r);
}

// A-fragments (fp16 RTN): set f = kd*2 + cht (6 sets); dword i = f*256 + lane*4 + r.
// Lane l holds A[ch = cht*16 + (l&15)][slot (g=l>>4, j=2r+half)] = weight of tap
// TAP[g][j] (0 for pads). Must match the kernel's B-side gather.
__global__ void prep_weights(const float* __restrict__ w, unsigned* __restrict__ ws) {
    static constexpr int TAP[4][8] = TAP_TABLE;
    int i = blockIdx.x * 256 + threadIdx.x;          // 1536 dwords
    if (i >= 1536) return;
    int f = i >> 8, rem = i & 255;
    int lane = rem >> 2, r = rem & 3;
    int kd = f >> 1, cht = f & 1;
    int g = lane >> 4, chl = lane & 15;
    int ch = cht * 16 + chl;
    unsigned outv = 0;
    for (int half = 0; half < 2; ++half) {
        int t = TAP[g][2 * r + half];
        unsigned short bits = 0;                     // exact zero for pad slots
        if (ch < 24 && t >= 0) {
            int ci = t / 9, rr = t % 9, kh = rr / 3, kw = rr % 3;
            union { _Float16 h; unsigned short u; } cv;
            cv.h = (_Float16)w[(((ch * 3 + ci) * 3 + kd) * 3 + kh) * 3 + kw];
            bits = cv.u;
        }
        outv |= (unsigned)bits << (16 * half);
    }
    ws[i] = outv;
}

__global__ __launch_bounds__(256, 3) void conv_mfma(
    const float* __restrict__ x, const char* __restrict__ wsp,
    const float* __restrict__ bias, float* __restrict__ out)
{
    static constexpr int TAP[4][8] = TAP_TABLE;
    // 5-slot ring of SHARED slices: [slot][ci 0..2][row 0..5][col 0..31], row-rotated
    __shared__ __align__(16) float xs[5 * 576];      // 11520 B

    const int tid  = threadIdx.x;
    const int lane = tid & 63;
    const int wid  = tid >> 6;
    const int g = lane >> 4, m = lane & 15;
    // XCD-bijective swizzle (2048 % 8 == 0): XCD k owns n in [32k, 32k+32)
    const int lb = (blockIdx.x & 7) * 256 + (blockIdx.x >> 3);
    const int n  = lb >> 3;
    const int h0 = (lb & 7) * 4;                     // h-tile base: 0,4,...,28
    const int h  = h0 + wid;
    const bool hOK = (h < 30);

    // ---- strip staging (wave wid<3 stages ci=wid): 6 rows x 32 cols = 768 B
    const int srow = lane >> 3;                      // 0..5 for lanes 0..47
    const int sc4  = (lane & 7) * 4;
    const int scol = (sc4 - 8 * (srow & 3)) & 31;    // pre-rotated source col
    const int limS = (h0 == 28) ? 32 : 48;           // clip rows > 31 at last tile
    const int ciS  = (wid < 3) ? wid : 0;
    const char* gsb = (const char*)(x + ((size_t)(n * 3 + ciS) * 32768
                                          + (size_t)(h0 + srow) * 32 + scol));

    auto stageTo = [&](int slotFl, int s) {          // one DMA instr per staging wave
        if (wid < 3 && lane < limS)
            __builtin_amdgcn_global_load_lds(
                (const __attribute__((address_space(1))) unsigned*)(gsb + (size_t)s * 4096),
                (__attribute__((address_space(3))) unsigned*)(xs + slotFl + wid * 192),
                16, 0, 0);
    };

    // ---- gather addresses: byte offset within a slot for tap t (wt variant)
    auto mkidx = [&](int t, int wt) -> unsigned {
        if (t >= 0) {
            int ci = t / 9, rr = t % 9, kh = rr / 3, kw = rr % 3;
            int row = wid + kh;                      // 0..5
            int col = (m + wt * 14 + kw + 8 * (row & 3)) & 31;
            return (unsigned)((ci * 192 + row * 32 + col) * 4);
        } else {                                     // pad: engineered bank class
            int V = -t;                              // 24..26
            int col = (m + wt * 14 + V + 8 * (wid & 3)) & 31;
            return (unsigned)((wid * 32 + col) * 4); // row<=3: always staged, finite
        }
    };
    unsigned bp[2][2], apoS[2][4];
#pragma unroll
    for (int wt = 0; wt < 2; ++wt) {
        bp[wt][0] = mkidx(TAP[g][0], wt);            // RP1 base (phase1 = +192 dwords)
        bp[wt][1] = mkidx(TAP[g][2], wt);            // RP2 base
#pragma unroll
        for (int j = 0; j < 4; ++j) apoS[wt][j] = mkidx(TAP[g][4 + j], wt);
    }

    // ---- preload 6 A-fragments (loop-invariant, 24 VGPRs)
    const char* wl = wsp + (size_t)lane * 16;
    f16x8 aH[3][2];
#pragma unroll
    for (int kd = 0; kd < 3; ++kd)
#pragma unroll
        for (int cht = 0; cht < 2; ++cht)
            aH[kd][cht] = *(const f16x8*)(wl + (size_t)(kd * 2 + cht) * 1024);

    f32x4 acc[3][2][2];                              // [depth%3][cht][wt]; fresh at kd=0
    f32x4 mn[2][2];
#pragma unroll
    for (int b = 0; b < 2; ++b)
#pragma unroll
        for (int c = 0; c < 2; ++c) mn[b][c] = (f32x4){FLT_MAX, FLT_MAX, FLT_MAX, FLT_MAX};
    const f32x4 ZR = (f32x4){0.f, 0.f, 0.f, 0.f};

    stageTo(0, 0); stageTo(576, 1); stageTo(1152, 2); stageTo(1728, 3);  // 3-deep prologue

    const char* xb = (const char*)xs;

    auto step = [&](auto sc) {
        constexpr int  S    = decltype(sc)::value;
        constexpr int  SLOT = (S % 5) * 2304;        // byte offset of slice S
        constexpr int  SM   = S % 3;
        constexpr bool K0 = (S <= 29), K1 = (S >= 1 && S <= 30), K2 = (S >= 2);

        // drain own DMA for slice S; keep 3 youngest prefetches in flight
        if constexpr (S <= 28)      asm volatile("s_waitcnt vmcnt(3)\ns_barrier" ::: "memory");
        else if constexpr (S == 29) asm volatile("s_waitcnt vmcnt(2)\ns_barrier" ::: "memory");
        else if constexpr (S == 30) asm volatile("s_waitcnt vmcnt(1)\ns_barrier" ::: "memory");
        else                        asm volatile("s_waitcnt vmcnt(0)\ns_barrier" ::: "memory");
        if constexpr (S + 4 <= 31) stageTo(((S + 4) % 5) * 576, S + 4);  // into retired slot
        __builtin_amdgcn_sched_barrier(0);

        if (hOK) {
#pragma unroll
            for (int wt = 0; wt < 2; ++wt) {
                float xv[8];
                // pair reads: ds_read2_b32 offset0:0 offset1:192 (delta ci->ci+1)
                const float* q0 = (const float*)(xb + SLOT + bp[wt][0]);
                xv[0] = q0[0]; xv[1] = q0[192];
                const float* q1 = (const float*)(xb + SLOT + bp[wt][1]);
                xv[2] = q1[0]; xv[3] = q1[192];
#pragma unroll
                for (int j = 0; j < 4; ++j)          // singles (imm-offset b32)
                    xv[4 + j] = *(const float*)(xb + SLOT + apoS[wt][j]);
                f16x2 p0 = pkrtz(xv[0], xv[1]);
                f16x2 p1 = pkrtz(xv[2], xv[3]);
                f16x2 p2 = pkrtz(xv[4], xv[5]);
                f16x2 p3 = pkrtz(xv[6], xv[7]);
                f16x4 lo = __builtin_shufflevector(p0, p1, 0, 1, 2, 3);
                f16x4 hi = __builtin_shufflevector(p2, p3, 0, 1, 2, 3);
                f16x8 bf = __builtin_shufflevector(lo, hi, 0, 1, 2, 3, 4, 5, 6, 7);
                if constexpr (K0) {                  // fresh depth S from zero C
                    acc[SM][0][wt] = MM(aH[0][0], bf, ZR);
                    acc[SM][1][wt] = MM(aH[0][1], bf, ZR);
                }
                if constexpr (K1) {
                    constexpr int S1 = (SM + 2) % 3;
                    acc[S1][0][wt] = MM(aH[1][0], bf, acc[S1][0][wt]);
                    acc[S1][1][wt] = MM(aH[1][1], bf, acc[S1][1][wt]);
                }
                if constexpr (K2) {
                    constexpr int S2 = (SM + 1) % 3;
                    acc[S2][0][wt] = MM(aH[2][0], bf, acc[S2][0][wt]);
                    acc[S2][1][wt] = MM(aH[2][1], bf, acc[S2][1][wt]);
                }
            }
            if constexpr (K2) {                      // retire depth S-2
                constexpr int S2 = (SM + 1) % 3;
#pragma unroll
                for (int cht = 0; cht < 2; ++cht)
#pragma unroll
                    for (int wt = 0; wt < 2; ++wt)
#pragma unroll
                        for (int r = 0; r < 4; ++r)
                            mn[cht][wt][r] = fminf(mn[cht][wt][r], acc[S2][cht][wt][r]);
            }
        }
    };

#define STEP(S) step(std::integral_constant<int, S>{})
    STEP(0);  STEP(1);  STEP(2);  STEP(3);  STEP(4);  STEP(5);  STEP(6);  STEP(7);
    STEP(8);  STEP(9);  STEP(10); STEP(11); STEP(12); STEP(13); STEP(14); STEP(15);
    STEP(16); STEP(17); STEP(18); STEP(19); STEP(20); STEP(21); STEP(22); STEP(23);
    STEP(24); STEP(25); STEP(26); STEP(27); STEP(28); STEP(29); STEP(30); STEP(31);
#undef STEP

    // ---- bias + softmax over channels (lanes m, m+16, m+32, m+48 hold one column)
    if (hOK) {
#pragma unroll
        for (int wt = 0; wt < 2; ++wt) {
            float vals[8];
            float mx = -FLT_MAX;
#pragma unroll
            for (int cht = 0; cht < 2; ++cht)
#pragma unroll
                for (int r = 0; r < 4; ++r) {
                    int c  = cht * 16 + 4 * g + r;
                    int cc = (c < 24) ? c : 0;       // guard OOB bias load
                    float val = mn[cht][wt][r] + bias[cc];
                    if (c >= 24) val = -FLT_MAX;
                    vals[cht * 4 + r] = val;
                    mx = fmaxf(mx, val);
                }
            mx = fmaxf(mx, __shfl_xor(mx, 16));
            mx = fmaxf(mx, __shfl_xor(mx, 32));
            float sum = 0.f;
#pragma unroll
            for (int jj = 0; jj < 8; ++jj) {
                float e = (vals[jj] > -FLT_MAX * 0.5f) ? expf(vals[jj] - mx) : 0.f;
                vals[jj] = e;
                sum += e;
            }
            sum += __shfl_xor(sum, 16);
            sum += __shfl_xor(sum, 32);
            const float inv = 1.0f / sum;
            const int w = wt * 14 + m;               // wt0: 0..15; wt1: 16..29 (m>=2)
            if (wt == 0 || m >= 2) {
#pragma unroll
                for (int cht = 0; cht < 2; ++cht)
#pragma unroll
                    for (int r = 0; r < 4; ++r) {
                        int c = cht * 16 + 4 * g + r;
                        if (c < 24)
                            out[((size_t)(n * 24 + c) * 30 + h) * 30 + w]
                                = vals[cht * 4 + r] * inv;
                    }
            }
        }
    }
}

extern "C" void kernel_launch(void* const* d_in, const int* in_sizes, int n_in,
                              void* d_out, int out_size, void* d_ws, size_t ws_size,
                              hipStream_t stream) {
    const float* x    = (const float*)d_in[0];
    const float* wgt  = (const float*)d_in[1];
    const float* bias = (const float*)d_in[2];
    prep_weights<<<6, 256, 0, stream>>>(wgt, (unsigned*)d_ws);      // 6144 B of d_ws
    conv_mfma<<<N_BATCH * 8, 256, 0, stream>>>(x, (const char*)d_ws, bias, (float*)d_out);
}